// Round 1
// baseline (160.432 us; speedup 1.0000x reference)
//
#include <hip/hip_runtime.h>

// Problem constants (QuantLinearW4A4Tl): M=8192, K=4096, N=4096, R=32
#define M_ 8192
#define K_ 4096
#define N_ 4096
#define R_ 32
#define KP_ (K_ / 2)   // packed int32 per row (2 nibbles per int32)

#define BM 128
#define BN 128
#define BK 128         // int8 k per K-step

typedef __attribute__((ext_vector_type(4))) int    i32x4;
typedef __attribute__((ext_vector_type(4))) float  f32x4;
typedef __attribute__((ext_vector_type(8))) __bf16 bf16x8;

__device__ __forceinline__ void gload16(const void* g, void* l) {
  __builtin_amdgcn_global_load_lds(
      (const __attribute__((address_space(1))) unsigned int*)g,
      (__attribute__((address_space(3))) unsigned int*)l, 16, 0, 0);
}

// ---- repack: int32 (2 nibbles, value 0..255) -> 2 sign-extended int8 ----
__device__ __forceinline__ unsigned nib2(int b) {
  unsigned lo = (unsigned)(((b & 15) ^ 8) - 8) & 0xFFu;
  unsigned hi = (unsigned)((((b >> 4) & 15) ^ 8) - 8) & 0xFFu;
  return lo | (hi << 8);
}

__global__ void repack_int4(const int* __restrict__ in, unsigned* __restrict__ out, int n4) {
  int stride = gridDim.x * blockDim.x;
  for (int i = blockIdx.x * blockDim.x + threadIdx.x; i < n4; i += stride) {
    int4 v = ((const int4*)in)[i];
    uint2 o;
    o.x = nib2(v.x) | (nib2(v.y) << 16);
    o.y = nib2(v.z) | (nib2(v.w) << 16);
    ((uint2*)out)[i] = o;
  }
}

// ---- f32 -> bf16 (RNE) for the low-rank outlier operands ----
__device__ __forceinline__ unsigned short f2b(float x) {
  unsigned u = __float_as_uint(x);
  return (unsigned short)((u + 0x7FFFu + ((u >> 16) & 1u)) >> 16);
}

__global__ void f2bf4(const float* __restrict__ in, unsigned short* __restrict__ out, int n4) {
  int stride = gridDim.x * blockDim.x;
  for (int i = blockIdx.x * blockDim.x + threadIdx.x; i < n4; i += stride) {
    float4 f = ((const float4*)in)[i];
    ushort4 o;
    o.x = f2b(f.x); o.y = f2b(f.y); o.z = f2b(f.z); o.w = f2b(f.w);
    ((ushort4*)out)[i] = o;
  }
}

// ---- main GEMM: 128x128 tile, BK=128 i8, 4 waves of 64x64, fused epilogue ----
__global__ __launch_bounds__(256, 3) void gemm_w4a4(
    const signed char* __restrict__ x8, const signed char* __restrict__ w8,
    const unsigned short* __restrict__ xrb, const unsigned short* __restrict__ wob,
    const float* __restrict__ xscale, const float* __restrict__ wscale,
    const float* __restrict__ bias, float* __restrict__ out)
{
  __shared__ __align__(16) signed char lds[2 * BM * BK];  // 32 KiB: A then B
  signed char* As = lds;
  signed char* Bs = lds + BM * BK;

  const int t    = threadIdx.x;
  const int w    = t >> 6;          // wave id 0..3
  const int lrow = t & 15;          // lane & 15
  const int lgrp = (t >> 4) & 3;    // lane >> 4
  const int wr   = w >> 1, wc = w & 1;
  const int m0   = (blockIdx.x & 63) * BM;
  const int n0   = (blockIdx.x >> 6) * BN;

  i32x4 acc[4][4] = {};

  for (int kt = 0; kt < K_ / BK; ++kt) {
    __syncthreads();  // previous tile's reads done before overwrite
    const size_t kb = (size_t)kt * BK;
    // stage A and B: 16 KiB each, 4 rounds x 256 thr x 16 B.
    // LDS dest is linear (global_load_lds requirement); the XOR swizzle is
    // applied on the GLOBAL source so reads can un-swizzle (m173/m201 rule).
    #pragma unroll
    for (int i = 0; i < 4; ++i) {
      int idx  = i * 4096 + t * 16;          // linear LDS byte
      int row  = idx >> 7;                   // 128 B per row
      int gcol = (((idx >> 4) & 7) ^ (row & 7)) << 4;
      gload16(x8 + (size_t)(m0 + row) * K_ + kb + gcol, As + i * 4096 + (w << 10));
      gload16(w8 + (size_t)(n0 + row) * K_ + kb + gcol, Bs + i * 4096 + (w << 10));
    }
    __syncthreads();  // compiler drains vmcnt before barrier -> tiles ready
    #pragma unroll
    for (int ks = 0; ks < 2; ++ks) {         // two k-subtiles of 64
      i32x4 af[4], bf[4];
      #pragma unroll
      for (int f = 0; f < 4; ++f) {
        int ra = wr * 64 + f * 16 + lrow;
        af[f] = *(const i32x4*)(As + ra * BK + ((((ks << 2) + lgrp) ^ (ra & 7)) << 4));
        int rb = wc * 64 + f * 16 + lrow;
        bf[f] = *(const i32x4*)(Bs + rb * BK + ((((ks << 2) + lgrp) ^ (rb & 7)) << 4));
      }
      #pragma unroll
      for (int fm = 0; fm < 4; ++fm)
        #pragma unroll
        for (int fn = 0; fn < 4; ++fn)
          acc[fm][fn] = __builtin_amdgcn_mfma_i32_16x16x64_i8(af[fm], bf[fn], acc[fm][fn], 0, 0, 0);
    }
  }

  // ---- epilogue: dequant + bias + rank-32 outlier correction via bf16 MFMA ----
  float swv[4], bv[4];
  #pragma unroll
  for (int fn = 0; fn < 4; ++fn) {
    int cg = n0 + wc * 64 + fn * 16 + lrow;
    swv[fn] = wscale[cg];
    bv[fn]  = bias[cg];
  }
  float sxv[4][4];
  #pragma unroll
  for (int fm = 0; fm < 4; ++fm)
    #pragma unroll
    for (int j = 0; j < 4; ++j)
      sxv[fm][j] = xscale[m0 + wr * 64 + fm * 16 + lgrp * 4 + j];

  __syncthreads();  // all waves done with last K-tile's LDS reads
  // stage x_r tile [128][32] bf16 (8 KiB) and w_outlier tile (8 KiB)
  #pragma unroll
  for (int i = 0; i < 2; ++i) {
    int idx = i * 4096 + t * 16;
    int row = idx >> 6, col = idx & 63;      // 64 B per row
    gload16((const char*)xrb + (size_t)(m0 + row) * 64 + col, lds + i * 4096 + (w << 10));
    gload16((const char*)wob + (size_t)(n0 + row) * 64 + col, lds + 8192 + i * 4096 + (w << 10));
  }
  __syncthreads();

  const unsigned short* xr_s = (const unsigned short*)lds;
  const unsigned short* wo_s = (const unsigned short*)(lds + 8192);
  bf16x8 ar[4], br[4];
  #pragma unroll
  for (int f = 0; f < 4; ++f) {
    ar[f] = *(const bf16x8*)(xr_s + (wr * 64 + f * 16 + lrow) * 32 + lgrp * 8);
    br[f] = *(const bf16x8*)(wo_s + (wc * 64 + f * 16 + lrow) * 32 + lgrp * 8);
  }
  #pragma unroll
  for (int fm = 0; fm < 4; ++fm) {
    #pragma unroll
    for (int fn = 0; fn < 4; ++fn) {
      f32x4 z = {0.0f, 0.0f, 0.0f, 0.0f};
      f32x4 c = __builtin_amdgcn_mfma_f32_16x16x32_bf16(ar[fm], br[fn], z, 0, 0, 0);
      #pragma unroll
      for (int j = 0; j < 4; ++j) {
        int rg = m0 + wr * 64 + fm * 16 + lgrp * 4 + j;  // C/D: row=(l>>4)*4+j
        int cg = n0 + wc * 64 + fn * 16 + lrow;          //      col=l&15
        out[(size_t)rg * N_ + cg] =
            (float)acc[fm][fn][j] * sxv[fm][j] * swv[fn] + c[j] + bv[fn];
      }
    }
  }
}

extern "C" void kernel_launch(void* const* d_in, const int* in_sizes, int n_in,
                              void* d_out, int out_size, void* d_ws, size_t ws_size,
                              hipStream_t stream) {
  const int*   x_quant   = (const int*)d_in[0];
  const float* x_scale   = (const float*)d_in[1];
  const int*   weight    = (const int*)d_in[2];
  const float* w_scales  = (const float*)d_in[3];
  const float* bias      = (const float*)d_in[4];
  const float* x_r       = (const float*)d_in[5];
  const float* w_outlier = (const float*)d_in[6];
  float* out = (float*)d_out;

  // workspace layout (needs ~48.75 MiB)
  char* ws = (char*)d_ws;
  signed char*    x8  = (signed char*)ws;                               // 32 MiB
  signed char*    w8  = (signed char*)(ws + (size_t)M_ * K_);           // 16 MiB
  unsigned short* xrb = (unsigned short*)(ws + (size_t)M_ * K_ + (size_t)N_ * K_);  // 512 KiB
  unsigned short* wob = xrb + (size_t)M_ * R_;                          // 256 KiB

  repack_int4<<<2048, 256, 0, stream>>>(x_quant, (unsigned*)x8, M_ * KP_ / 4);
  repack_int4<<<2048, 256, 0, stream>>>(weight,  (unsigned*)w8, N_ * KP_ / 4);
  f2bf4<<<256, 256, 0, stream>>>(x_r, xrb, M_ * R_ / 4);
  f2bf4<<<128, 256, 0, stream>>>(w_outlier, wob, N_ * R_ / 4);

  gemm_w4a4<<<(M_ / BM) * (N_ / BN), 256, 0, stream>>>(
      x8, w8, xrb, wob, x_scale, w_scales, bias, out);
}